// Round 2
// baseline (2140.437 us; speedup 1.0000x reference)
//
#include <hip/hip_runtime.h>
#include <hip/hip_bf16.h>

typedef unsigned int uint;
typedef unsigned short ushort;

// ---------------- table region offsets (in floats) ----------------
#define T_WQ 0
#define T_WK 49152
#define T_WV 98304
#define T_BQ 147456
#define T_BK 147840
#define T_BV 148224
#define T_RQ 148608
#define T_RK 149632
#define T_RV 150656
#define T_RB 151680
#define T_SK 151744
#define T_SV 152128
#define T_TOTAL 152512

__device__ __forceinline__ float bf2f(ushort u) { return __uint_as_float(((uint)u) << 16); }
__device__ __forceinline__ ushort f2bf(float f) {
  uint x = __float_as_uint(f);
  return (ushort)((x + 0x7fffu + ((x >> 16) & 1u)) >> 16);
}
// dual-dtype input load: bf=1 -> packed bf16, bf=0 -> fp32
__device__ __forceinline__ float ldin(const void* p, size_t i, int bf) {
  return bf ? bf2f(((const ushort*)p)[i]) : ((const float*)p)[i];
}

// ---------------- dtype detector: 1 wave ----------------
// Decode first 64 words of node_inp as bf16 pairs. In a bf16 world all 128
// values are plausible N(0,1) magnitudes; in an fp32 world the low halves
// have uniform-random exponents (~90% implausible).
__global__ void detect_kernel(const uint* __restrict__ x, int* __restrict__ flag) {
  int lane = threadIdx.x & 63;
  uint u = x[lane];
  float a = __uint_as_float(u << 16);
  float b = __uint_as_float(u & 0xffff0000u);
  float fa = fabsf(a), fb = fabsf(b);
  int cnt = 0;
  if (!(fa >= 1e-7f && fa <= 256.f)) cnt++;
  if (!(fb >= 1e-7f && fb <= 256.f)) cnt++;
#pragma unroll
  for (int m = 1; m < 64; m <<= 1) cnt += __shfl_xor(cnt, m);
  if (lane == 0) flag[0] = (cnt < 8) ? 1 : 0;
}

// ---------------- convert all small tables -> fp32 ----------------
__global__ __launch_bounds__(256) void cvt_kernel(
    const void* __restrict__ wq, const void* __restrict__ wk, const void* __restrict__ wv,
    const void* __restrict__ bq, const void* __restrict__ bk, const void* __restrict__ bv,
    const void* __restrict__ rq, const void* __restrict__ rk, const void* __restrict__ rv,
    const void* __restrict__ rb,
    const void* __restrict__ skf, const void* __restrict__ svf,
    const void* __restrict__ skn, const void* __restrict__ svn,
    float* __restrict__ tab, const int* __restrict__ bff) {
  const int bf = bff[0];
  int i = blockIdx.x * 256 + threadIdx.x;
  if (i < 49152) {
    tab[T_WQ + i] = ldin(wq, i, bf);
    tab[T_WK + i] = ldin(wk, i, bf);
    tab[T_WV + i] = ldin(wv, i, bf);
  }
  if (i < 1024) {
    tab[T_RQ + i] = ldin(rq, i, bf);
    tab[T_RK + i] = ldin(rk, i, bf);
    tab[T_RV + i] = ldin(rv, i, bf);
  }
  if (i < 384) {
    tab[T_BQ + i] = ldin(bq, i, bf);
    tab[T_BK + i] = ldin(bk, i, bf);
    tab[T_BV + i] = ldin(bv, i, bf);
    // sign tables: [0]=neg fixed, [1]=pos fixed, [2]=neutral (each 128 = H*DK)
    tab[T_SK + i] = (i < 256) ? ldin(skf, i, bf) : ldin(skn, i - 256, bf);
    tab[T_SV + i] = (i < 256) ? ldin(svf, i, bf) : ldin(svn, i - 256, bf);
  }
  if (i < 64) tab[T_RB + i] = ldin(rb, i, bf);
}

// ---------------- per-type QKV projection ----------------
// 32 nodes/block (4 waves x 8 nodes), each lane computes 2 consecutive channels.
__global__ __launch_bounds__(256) void proj_kernel(
    const void* __restrict__ xin, const int* __restrict__ ntype,
    const float* __restrict__ tab,
    float* __restrict__ Q, float* __restrict__ K, float* __restrict__ V, int N,
    const int* __restrict__ bff) {
  __shared__ float xs[32 * 128];
  const int bf = bff[0];
  const int tid = threadIdx.x;
  const int nb0 = blockIdx.x * 32;
  for (int r = tid; r < 32 * 64; r += 256) {
    int n = r >> 6, dw = r & 63;
    int node = nb0 + n;
    if (node < N) {
      if (bf) {
        uint u = ((const uint*)xin)[(size_t)node * 64 + dw];
        xs[n * 128 + dw * 2]     = __uint_as_float(u << 16);
        xs[n * 128 + dw * 2 + 1] = __uint_as_float(u & 0xffff0000u);
      } else {
        float2 v = ((const float2*)xin)[(size_t)node * 64 + dw];
        xs[n * 128 + dw * 2]     = v.x;
        xs[n * 128 + dw * 2 + 1] = v.y;
      }
    } else {
      xs[n * 128 + dw * 2] = 0.f;
      xs[n * 128 + dw * 2 + 1] = 0.f;
    }
  }
  __syncthreads();
  const int lane = tid & 63;
  const int nbase = (tid >> 6) * 8;
  const int o2 = lane * 2;

  float aqx[8], aqy[8], akx[8], aky[8], avx[8], avy[8];
  int tb[8];
#pragma unroll
  for (int n = 0; n < 8; ++n) {
    int node = nb0 + nbase + n;
    int t = (node < N) ? ntype[node] : 0;
    tb[n] = t * 16384;
    aqx[n] = tab[T_BQ + t * 128 + o2]; aqy[n] = tab[T_BQ + t * 128 + o2 + 1];
    akx[n] = tab[T_BK + t * 128 + o2]; aky[n] = tab[T_BK + t * 128 + o2 + 1];
    avx[n] = tab[T_BV + t * 128 + o2]; avy[n] = tab[T_BV + t * 128 + o2 + 1];
  }
  const float* __restrict__ Wq = tab + T_WQ;
  const float* __restrict__ Wk = tab + T_WK;
  const float* __restrict__ Wv = tab + T_WV;
  for (int d = 0; d < 128; ++d) {
#pragma unroll
    for (int n = 0; n < 8; ++n) {
      float xv = xs[(nbase + n) * 128 + d];
      int off = tb[n] + d * 128 + o2;
      float2 wqv = *(const float2*)(Wq + off);
      float2 wkv = *(const float2*)(Wk + off);
      float2 wvv = *(const float2*)(Wv + off);
      aqx[n] = fmaf(xv, wqv.x, aqx[n]); aqy[n] = fmaf(xv, wqv.y, aqy[n]);
      akx[n] = fmaf(xv, wkv.x, akx[n]); aky[n] = fmaf(xv, wkv.y, aky[n]);
      avx[n] = fmaf(xv, wvv.x, avx[n]); avy[n] = fmaf(xv, wvv.y, avy[n]);
    }
  }
#pragma unroll
  for (int n = 0; n < 8; ++n) {
    int node = nb0 + nbase + n;
    if (node < N) {
      size_t base = (size_t)node * 128 + o2;
      float2 q; q.x = aqx[n]; q.y = aqy[n];
      float2 k; k.x = akx[n]; k.y = aky[n];
      float2 v; v.x = avx[n]; v.y = avy[n];
      *(float2*)(Q + base) = q;
      *(float2*)(K + base) = k;
      *(float2*)(V + base) = v;
    }
  }
}

// ---------------- edge attention: scores + exp + atomic accumulate ----------------
// one wave per edge; lane = h*8 + j, lane handles dk pair (2j, 2j+1)
__global__ __launch_bounds__(256) void edge_kernel(
    const float* __restrict__ Q, const float* __restrict__ K, const float* __restrict__ V,
    const int* __restrict__ esrc, const int* __restrict__ edst,
    const int* __restrict__ etype, const int* __restrict__ esign,
    const void* __restrict__ edist,
    const float* __restrict__ tab,
    const void* __restrict__ p_alpha, const void* __restrict__ p_tau,
    float* __restrict__ Z, float* __restrict__ OUT, int E,
    const int* __restrict__ bff) {
  int e = blockIdx.x * 4 + (threadIdx.x >> 6);
  if (e >= E) return;
  const int bf = bff[0];
  int lane = threadIdx.x & 63;
  int h = lane >> 3, j = lane & 7;
  int c = h * 16 + j * 2;

  int src = esrc[e], dst = edst[e];
  int et = etype[e], sg = esign[e];
  int sidx = (sg == -1) ? 0 : ((sg == 1) ? 1 : 2);
  float alpha = ldin(p_alpha, 0, bf);
  float tau   = ldin(p_tau, 0, bf);
  float dist  = ldin(edist, e, bf);
  // legit arg is in [-2, 0]; clamps are no-ops unless inputs are garbage
  float parg = fminf(fmaxf(-dist / (tau + 1e-9f), -80.f), 0.f);
  float phi = alpha * __expf(parg);

  size_t qb = (size_t)dst * 128 + c;
  size_t kb = (size_t)src * 128 + c;
  float2 q = *(const float2*)(Q + qb);
  float2 k = *(const float2*)(K + kb);
  float2 v = *(const float2*)(V + kb);
  int rc = et * 128 + c;
  float2 rqv = *(const float2*)(tab + T_RQ + rc);
  float2 rkv = *(const float2*)(tab + T_RK + rc);
  float2 rvv = *(const float2*)(tab + T_RV + rc);
  int scn = sidx * 128 + c;
  float2 skv = *(const float2*)(tab + T_SK + scn);
  float2 svv = *(const float2*)(tab + T_SV + scn);

  float qex = q.x * rqv.x, qey = q.y * rqv.y;
  float kex = k.x * rkv.x * skv.x, key = k.y * rkv.y * skv.y;
  float s = qex * kex + qey * key;
  s += __shfl_xor(s, 1);
  s += __shfl_xor(s, 2);
  s += __shfl_xor(s, 4);
  // scores tiny (|s*0.25|<~2): safe to skip segment-max. Clamp is a no-op
  // for legit data; prevents Inf->NaN propagation otherwise.
  float score = fminf(s * 0.25f + tab[T_RB + et * 8 + h] + phi, 80.f);
  float es = __expf(score);
  if (j == 0) unsafeAtomicAdd(&Z[(size_t)dst * 8 + h], es);
  float mx = es * v.x * rvv.x * svv.x;
  float my = es * v.y * rvv.y * svv.y;
  float* op = OUT + (size_t)dst * 128 + c;
  unsafeAtomicAdd(op, mx);
  unsafeAtomicAdd(op + 1, my);
}

// ---------------- finalize: normalize, gated residual, LayerNorm, store ----------------
__global__ __launch_bounds__(256) void final_kernel(
    const float* __restrict__ OUT, const float* __restrict__ Z,
    const void* __restrict__ xin, const int* __restrict__ ntype,
    const void* __restrict__ skip, const void* __restrict__ gamma,
    const void* __restrict__ beta, void* __restrict__ y, int N,
    const int* __restrict__ bff) {
  int node = blockIdx.x * 4 + (threadIdx.x >> 6);
  if (node >= N) return;
  const int bf = bff[0];
  int lane = threadIdx.x & 63;
  int c = lane * 2;
  int h = lane >> 3;

  float2 acc = *(const float2*)(OUT + (size_t)node * 128 + c);
  float zh = Z[(size_t)node * 8 + h];
  float inv = 1.0f / (zh + 1e-9f);
  float o0 = acc.x * inv, o1 = acc.y * inv;

  int t = ntype[node];
  float a = 1.0f / (1.0f + __expf(-ldin(skip, t, bf)));
  float xi0, xi1;
  if (bf) {
    uint xu = ((const uint*)xin)[(size_t)node * 64 + lane];
    xi0 = __uint_as_float(xu << 16);
    xi1 = __uint_as_float(xu & 0xffff0000u);
  } else {
    float2 xv = ((const float2*)xin)[(size_t)node * 64 + lane];
    xi0 = xv.x; xi1 = xv.y;
  }
  float v0 = a * o0 + (1.0f - a) * xi0;
  float v1 = a * o1 + (1.0f - a) * xi1;

  float sum = v0 + v1, sq = v0 * v0 + v1 * v1;
#pragma unroll
  for (int m = 1; m < 64; m <<= 1) {
    sum += __shfl_xor(sum, m);
    sq  += __shfl_xor(sq, m);
  }
  float mean = sum * (1.0f / 128.0f);
  float var = fmaxf(sq * (1.0f / 128.0f) - mean * mean, 0.0f);
  float rstd = rsqrtf(var + 1e-5f);

  float g0 = ldin(gamma, (size_t)t * 128 + c, bf);
  float g1 = ldin(gamma, (size_t)t * 128 + c + 1, bf);
  float b0 = ldin(beta, (size_t)t * 128 + c, bf);
  float b1 = ldin(beta, (size_t)t * 128 + c + 1, bf);
  float y0 = (v0 - mean) * rstd * g0 + b0;
  float y1 = (v1 - mean) * rstd * g1 + b1;
  if (bf) {
    uint pack = ((uint)f2bf(y1) << 16) | (uint)f2bf(y0);
    ((uint*)y)[(size_t)node * 64 + lane] = pack;
  } else {
    float2 o; o.x = y0; o.y = y1;
    ((float2*)y)[(size_t)node * 64 + lane] = o;
  }
}

extern "C" void kernel_launch(void* const* d_in, const int* in_sizes, int n_in,
                              void* d_out, int out_size, void* d_ws, size_t ws_size,
                              hipStream_t stream) {
  const void* xin   = d_in[0];                 // node_inp (bf16 or fp32, auto-detected)
  const int*  ntype = (const int*)d_in[1];
  const int*  eidx  = (const int*)d_in[2];     // [2,E]
  const int*  etype = (const int*)d_in[3];
  const int*  esign = (const int*)d_in[4];
  const void* edist = d_in[5];

  const int N = in_sizes[1];
  const int E = in_sizes[3];

  float* ws = (float*)d_ws;
  const size_t NQ = (size_t)N * 128;
  float* Q   = ws;
  float* K   = ws + NQ;
  float* V   = ws + 2 * NQ;
  float* Zp  = ws + 3 * NQ;
  float* OUT = Zp + (size_t)N * 8;
  float* tab = OUT + NQ;
  int*   bff = (int*)(tab + T_TOTAL);

  // zero Z + OUT (contiguous)
  hipMemsetAsync(Zp, 0, ((size_t)N * 8 + NQ) * sizeof(float), stream);
  detect_kernel<<<1, 64, 0, stream>>>((const uint*)xin, bff);
  cvt_kernel<<<192, 256, 0, stream>>>(d_in[6], d_in[8], d_in[10], d_in[7], d_in[9],
                                      d_in[11], d_in[12], d_in[13], d_in[14], d_in[15],
                                      d_in[16], d_in[17], d_in[18], d_in[19], tab, bff);
  proj_kernel<<<(N + 31) / 32, 256, 0, stream>>>(xin, ntype, tab, Q, K, V, N, bff);
  edge_kernel<<<(E + 3) / 4, 256, 0, stream>>>(Q, K, V, eidx, eidx + E, etype, esign,
                                               edist, tab, d_in[20], d_in[21], Zp, OUT, E,
                                               bff);
  final_kernel<<<(N + 3) / 4, 256, 0, stream>>>(OUT, Zp, xin, ntype, d_in[22], d_in[23],
                                                d_in[24], d_out, N, bff);
}

// Round 4
// 1181.177 us; speedup vs baseline: 1.8121x; 1.8121x over previous
//
#include <hip/hip_runtime.h>
#include <hip/hip_bf16.h>

typedef unsigned int uint;
typedef unsigned short ushort;
typedef unsigned long long ull;
typedef __attribute__((ext_vector_type(8))) short short8;
typedef __attribute__((ext_vector_type(4))) float f32x4;

// packed transposed W (bf16): [mat][t][o][d], mat-major; 147456 ushorts
#define WP_ELEMS 147456

__device__ __forceinline__ ushort f2bf(float f) {
  uint x = __float_as_uint(f);
  return (ushort)((x + 0x7fffu + ((x >> 16) & 1u)) >> 16);
}

// ---------------- cvt: W (fp32) -> packed transposed bf16; sign concat ----------------
__global__ __launch_bounds__(256) void cvt_kernel(
    const float* __restrict__ wq, const float* __restrict__ wk, const float* __restrict__ wv,
    const float* __restrict__ skf, const float* __restrict__ svf,
    const float* __restrict__ skn, const float* __restrict__ svn,
    ushort* __restrict__ Wp, float* __restrict__ sk, float* __restrict__ sv) {
  int i = blockIdx.x * 256 + threadIdx.x;
  if (i < WP_ELEMS) {
    int mat = i / 49152;
    int rem = i - mat * 49152;
    int t = rem >> 14;            // /16384
    int r2 = rem & 16383;
    int o = r2 >> 7;
    int d = r2 & 127;
    const float* src = (mat == 0) ? wq : (mat == 1) ? wk : wv;
    Wp[i] = f2bf(src[t * 16384 + d * 128 + o]);
  }
  if (i < 384) {
    // sign tables: [0]=neg fixed, [1]=pos fixed, [2]=neutral (each 128 = H*DK)
    sk[i] = (i < 256) ? skf[i] : skn[i - 256];
    sv[i] = (i < 256) ? svf[i] : svn[i - 256];
  }
}

// ---------------- type bucketing ----------------
__global__ __launch_bounds__(256) void count_kernel(const int* __restrict__ ntype,
                                                    int* __restrict__ cnt, int N) {
  int i = blockIdx.x * 256 + threadIdx.x;
  int lane = threadIdx.x & 63;
  int t = (i < N) ? ntype[i] : -1;
#pragma unroll
  for (int tt = 0; tt < 3; ++tt) {
    ull mask = __ballot(t == tt);
    if (mask) {
      int leader = __ffsll((long long)mask) - 1;
      if (lane == leader) atomicAdd(&cnt[tt], __popcll(mask));
    }
  }
}

__global__ void offs_kernel(const int* __restrict__ cnt, int* __restrict__ off) {
  int o = 0;
  off[0] = 0;
  for (int t = 0; t < 3; ++t) {
    o += ((cnt[t] + 63) >> 6) << 6;   // pad each bucket to 64
    off[t + 1] = o;
  }
}

__global__ __launch_bounds__(256) void fill_kernel(const int* __restrict__ ntype,
                                                   const int* __restrict__ off,
                                                   int* __restrict__ pos,
                                                   int* __restrict__ perm, int N) {
  int i = blockIdx.x * 256 + threadIdx.x;
  int lane = threadIdx.x & 63;
  int t = (i < N) ? ntype[i] : -1;
#pragma unroll
  for (int tt = 0; tt < 3; ++tt) {
    ull mask = __ballot(t == tt);
    if (mask) {
      int leader = __ffsll((long long)mask) - 1;
      int base = 0;
      if (lane == leader) base = atomicAdd(&pos[tt], __popcll(mask));
      base = __shfl(base, leader);
      if (t == tt) {
        int rank = __popcll(mask & ((lane == 63) ? 0x7fffffffffffffffull
                                                 : ((1ull << lane) - 1ull)));
        perm[off[tt] + base + rank] = i;
      }
    }
  }
}

// ---------------- MFMA QKV projection over type-sorted nodes ----------------
// 64 nodes/block, 4 waves x (16 rows x 128 cols) x 3 mats, K=128 via 4 mfma steps.
__global__ __launch_bounds__(256) void gemm_kernel(
    const float* __restrict__ X, const int* __restrict__ perm,
    const int* __restrict__ off, const ushort* __restrict__ Wp,
    const float* __restrict__ bq, const float* __restrict__ bk, const float* __restrict__ bv,
    float* __restrict__ Q, float* __restrict__ K, float* __restrict__ V) {
  __shared__ __align__(16) ushort As[64 * 136];   // pitch 136 bf16 (272B) -> 2-way LDS only
  __shared__ int prow[64];
  const int tid = threadIdx.x;
  const int base = blockIdx.x * 64;
  const int off1 = off[1], off2 = off[2], off3 = off[3];
  if (base >= off3) return;
  const int t = (base >= off1) + (base >= off2);

  if (tid < 64) prow[tid] = perm[base + tid];
  __syncthreads();
  // stage X rows: fp32 -> bf16 RNE pack into LDS
#pragma unroll
  for (int pass = 0; pass < 16; ++pass) {
    int row = pass * 4 + (tid >> 6);
    int dw = tid & 63;
    int p = prow[row];
    uint u = 0u;
    if (p >= 0) {
      float2 xv = *(const float2*)(X + (size_t)p * 128 + dw * 2);
      u = ((uint)f2bf(xv.y) << 16) | (uint)f2bf(xv.x);
    }
    ((uint*)As)[row * 68 + dw] = u;
  }
  __syncthreads();

  const int lane = tid & 63;
  const int w = tid >> 6;
  const int m0 = w * 16;
  const int r = lane & 15;
  const int q = lane >> 4;

  f32x4 acc[3][8];
#pragma unroll
  for (int m = 0; m < 3; ++m)
#pragma unroll
    for (int ot = 0; ot < 8; ++ot) acc[m][ot] = (f32x4){0.f, 0.f, 0.f, 0.f};

  const ushort* wbase = Wp + (size_t)t * 16384;   // + mat*49152 + o*128 + d
#pragma unroll
  for (int ks = 0; ks < 4; ++ks) {
    short8 a = *(const short8*)(As + (m0 + r) * 136 + ks * 32 + q * 8);
#pragma unroll
    for (int mat = 0; mat < 3; ++mat) {
#pragma unroll
      for (int ot = 0; ot < 8; ++ot) {
        short8 b = *(const short8*)(wbase + mat * 49152 + (ot * 16 + r) * 128 + ks * 32 + q * 8);
        acc[mat][ot] = __builtin_amdgcn_mfma_f32_16x16x32_bf16(a, b, acc[mat][ot], 0, 0, 0);
      }
    }
  }

  // epilogue: bias + scatter store (C layout: col=lane&15, row=quad*4+reg)
#pragma unroll
  for (int mat = 0; mat < 3; ++mat) {
    float* __restrict__ dstp = (mat == 0) ? Q : (mat == 1) ? K : V;
    const float* bias = (mat == 0) ? bq : (mat == 1) ? bk : bv;
#pragma unroll
    for (int ot = 0; ot < 8; ++ot) {
      int o = ot * 16 + r;
      float bi = bias[t * 128 + o];
#pragma unroll
      for (int reg = 0; reg < 4; ++reg) {
        int m = m0 + q * 4 + reg;
        int node = prow[m];
        if (node >= 0) dstp[(size_t)node * 128 + o] = acc[mat][ot][reg] + bi;
      }
    }
  }
}

// ---------------- edge attention: scores + exp + atomic accumulate ----------------
// one wave per edge; lane = h*8 + j, lane handles dk pair (2j, 2j+1)
__global__ __launch_bounds__(256) void edge_kernel(
    const float* __restrict__ Q, const float* __restrict__ K, const float* __restrict__ V,
    const int* __restrict__ esrc, const int* __restrict__ edst,
    const int* __restrict__ etype, const int* __restrict__ esign,
    const float* __restrict__ edist,
    const float* __restrict__ rq, const float* __restrict__ rk, const float* __restrict__ rv,
    const float* __restrict__ rb,
    const float* __restrict__ sk, const float* __restrict__ sv,
    const float* __restrict__ p_alpha, const float* __restrict__ p_tau,
    float* __restrict__ Z, float* __restrict__ OUT, int E) {
  int e = blockIdx.x * 4 + (threadIdx.x >> 6);
  if (e >= E) return;
  int lane = threadIdx.x & 63;
  int h = lane >> 3, j = lane & 7;
  int c = h * 16 + j * 2;

  int src = esrc[e], dst = edst[e];
  int et = etype[e], sg = esign[e];
  int sidx = (sg == -1) ? 0 : ((sg == 1) ? 1 : 2);
  float alpha = p_alpha[0];
  float tau   = p_tau[0];
  float dist  = edist[e];
  // legit arg in [-2,0]; clamp is a no-op for valid data, blocks Inf/NaN propagation
  float parg = fminf(fmaxf(-dist / (tau + 1e-9f), -80.f), 0.f);
  float phi = alpha * __expf(parg);

  size_t qb = (size_t)dst * 128 + c;
  size_t kb = (size_t)src * 128 + c;
  float2 qv = *(const float2*)(Q + qb);
  float2 kv = *(const float2*)(K + kb);
  float2 vv = *(const float2*)(V + kb);
  int rc = et * 128 + c;
  float2 rqv = *(const float2*)(rq + rc);
  float2 rkv = *(const float2*)(rk + rc);
  float2 rvv = *(const float2*)(rv + rc);
  int scn = sidx * 128 + c;
  float2 skv = *(const float2*)(sk + scn);
  float2 svv = *(const float2*)(sv + scn);

  float qex = qv.x * rqv.x, qey = qv.y * rqv.y;
  float kex = kv.x * rkv.x * skv.x, key = kv.y * rkv.y * skv.y;
  float s = qex * kex + qey * key;
  s += __shfl_xor(s, 1);
  s += __shfl_xor(s, 2);
  s += __shfl_xor(s, 4);
  // scores tiny (|s*0.25|<~1): safe to skip segment-max; clamp no-op for legit data
  float score = fminf(s * 0.25f + rb[et * 8 + h] + phi, 80.f);
  float es = __expf(score);
  if (j == 0) unsafeAtomicAdd(&Z[(size_t)dst * 8 + h], es);
  float mx = es * vv.x * rvv.x * svv.x;
  float my = es * vv.y * rvv.y * svv.y;
  float* op = OUT + (size_t)dst * 128 + c;
  unsafeAtomicAdd(op, mx);
  unsafeAtomicAdd(op + 1, my);
}

// ---------------- finalize: normalize, gated residual, LayerNorm, fp32 store ----------------
__global__ __launch_bounds__(256) void final_kernel(
    const float* __restrict__ OUT, const float* __restrict__ Z,
    const float* __restrict__ X, const int* __restrict__ ntype,
    const float* __restrict__ skip, const float* __restrict__ gamma,
    const float* __restrict__ beta, float* __restrict__ y, int N) {
  int node = blockIdx.x * 4 + (threadIdx.x >> 6);
  if (node >= N) return;
  int lane = threadIdx.x & 63;
  int c = lane * 2;
  int h = lane >> 3;

  float2 acc = *(const float2*)(OUT + (size_t)node * 128 + c);
  float zh = Z[(size_t)node * 8 + h];
  float inv = 1.0f / (zh + 1e-9f);
  float o0 = acc.x * inv, o1 = acc.y * inv;

  int t = ntype[node];
  float a = 1.0f / (1.0f + __expf(-skip[t]));
  float2 xv = *(const float2*)(X + (size_t)node * 128 + c);
  float v0 = a * o0 + (1.0f - a) * xv.x;
  float v1 = a * o1 + (1.0f - a) * xv.y;

  float sum = v0 + v1, sq = v0 * v0 + v1 * v1;
#pragma unroll
  for (int m = 1; m < 64; m <<= 1) {
    sum += __shfl_xor(sum, m);
    sq  += __shfl_xor(sq, m);
  }
  float mean = sum * (1.0f / 128.0f);
  float var = fmaxf(sq * (1.0f / 128.0f) - mean * mean, 0.0f);
  float rstd = rsqrtf(var + 1e-5f);

  float g0 = gamma[t * 128 + c], g1 = gamma[t * 128 + c + 1];
  float b0 = beta[t * 128 + c],  b1 = beta[t * 128 + c + 1];
  float2 o;
  o.x = (v0 - mean) * rstd * g0 + b0;
  o.y = (v1 - mean) * rstd * g1 + b1;
  *(float2*)(y + (size_t)node * 128 + c) = o;
}

extern "C" void kernel_launch(void* const* d_in, const int* in_sizes, int n_in,
                              void* d_out, int out_size, void* d_ws, size_t ws_size,
                              hipStream_t stream) {
  const float* X     = (const float*)d_in[0];
  const int*   ntype = (const int*)d_in[1];
  const int*   eidx  = (const int*)d_in[2];     // [2,E]
  const int*   etype = (const int*)d_in[3];
  const int*   esign = (const int*)d_in[4];
  const float* edist = (const float*)d_in[5];
  const float* wq = (const float*)d_in[6];
  const float* bq = (const float*)d_in[7];
  const float* wk = (const float*)d_in[8];
  const float* bk = (const float*)d_in[9];
  const float* wv = (const float*)d_in[10];
  const float* bv = (const float*)d_in[11];
  const float* rq = (const float*)d_in[12];
  const float* rk = (const float*)d_in[13];
  const float* rv = (const float*)d_in[14];
  const float* rb = (const float*)d_in[15];

  const int N = in_sizes[1];
  const int E = in_sizes[3];

  float* ws = (float*)d_ws;
  const size_t NQ = (size_t)N * 128;
  float* Q   = ws;
  float* K   = ws + NQ;
  float* V   = ws + 2 * NQ;
  float* Zp  = ws + 3 * NQ;
  float* OUT = Zp + (size_t)N * 8;
  float* skt = OUT + NQ;            // 384
  float* svt = skt + 384;           // 384
  ushort* Wp = (ushort*)(svt + 384);
  int* perm  = (int*)(svt + 384 + WP_ELEMS / 2);
  int* cnt   = perm + (N + 192);
  int* pos   = cnt + 4;
  int* off   = pos + 4;

  hipMemsetAsync(Zp, 0, ((size_t)N * 8 + NQ) * sizeof(float), stream);
  hipMemsetAsync(perm, 0xFF, (size_t)(N + 192) * sizeof(int), stream);
  hipMemsetAsync(cnt, 0, 8 * sizeof(int), stream);

  cvt_kernel<<<(WP_ELEMS + 255) / 256, 256, 0, stream>>>(
      wq, wk, wv, (const float*)d_in[16], (const float*)d_in[17],
      (const float*)d_in[18], (const float*)d_in[19], Wp, skt, svt);
  count_kernel<<<(N + 255) / 256, 256, 0, stream>>>(ntype, cnt, N);
  offs_kernel<<<1, 1, 0, stream>>>(cnt, off);
  fill_kernel<<<(N + 255) / 256, 256, 0, stream>>>(ntype, off, pos, perm, N);

  int maxtiles = (N + 255) / 64;    // >= off[3]/64 always
  gemm_kernel<<<maxtiles, 256, 0, stream>>>(X, perm, off, Wp, bq, bk, bv, Q, K, V);

  edge_kernel<<<(E + 3) / 4, 256, 0, stream>>>(Q, K, V, eidx, eidx + E, etype, esign,
                                               edist, rq, rk, rv, rb, skt, svt,
                                               (const float*)d_in[20], (const float*)d_in[21],
                                               Zp, OUT, E);
  final_kernel<<<(N + 3) / 4, 256, 0, stream>>>(OUT, Zp, X, ntype, (const float*)d_in[22],
                                                (const float*)d_in[23], (const float*)d_in[24],
                                                (float*)d_out, N);
}

// Round 5
// 773.081 us; speedup vs baseline: 2.7687x; 1.5279x over previous
//
#include <hip/hip_runtime.h>
#include <hip/hip_bf16.h>

typedef unsigned int uint;
typedef unsigned short ushort;
typedef unsigned long long ull;
typedef __attribute__((ext_vector_type(8))) short short8;
typedef __attribute__((ext_vector_type(4))) float f32x4;

// packed transposed W (bf16): [mat][t][o][d], mat-major; 147456 ushorts
#define WP_ELEMS 147456

__device__ __forceinline__ ushort f2bf(float f) {
  uint x = __float_as_uint(f);
  return (ushort)((x + 0x7fffu + ((x >> 16) & 1u)) >> 16);
}

// ---- cvt: W (fp32) -> packed transposed bf16; fused rel*sign tables ----
__global__ __launch_bounds__(256) void cvt_kernel(
    const float* __restrict__ wq, const float* __restrict__ wk, const float* __restrict__ wv,
    const float* __restrict__ rk, const float* __restrict__ rv,
    const float* __restrict__ skf, const float* __restrict__ svf,
    const float* __restrict__ skn, const float* __restrict__ svn,
    ushort* __restrict__ Wp, float* __restrict__ rksk, float* __restrict__ rvsv) {
  int i = blockIdx.x * 256 + threadIdx.x;
  if (i < WP_ELEMS) {
    int mat = i / 49152;
    int rem = i - mat * 49152;
    int t = rem >> 14;
    int r2 = rem & 16383;
    int o = r2 >> 7;
    int d = r2 & 127;
    const float* src = (mat == 0) ? wq : (mat == 1) ? wk : wv;
    Wp[i] = f2bf(src[t * 16384 + d * 128 + o]);
  }
  if (i < 3072) {            // comb = et*3+sidx (24) x c (128)
    int comb = i >> 7, c = i & 127;
    int et = comb / 3, sidx = comb - et * 3;
    float skv = (sidx < 2) ? skf[sidx * 128 + c] : skn[c];
    float svv = (sidx < 2) ? svf[sidx * 128 + c] : svn[c];
    rksk[i] = rk[et * 128 + c] * skv;
    rvsv[i] = rv[et * 128 + c] * svv;
  }
}

// ---------------- node type bucketing ----------------
__global__ __launch_bounds__(256) void count_kernel(const int* __restrict__ ntype,
                                                    int* __restrict__ cnt, int N) {
  int i = blockIdx.x * 256 + threadIdx.x;
  int lane = threadIdx.x & 63;
  int t = (i < N) ? ntype[i] : -1;
#pragma unroll
  for (int tt = 0; tt < 3; ++tt) {
    ull mask = __ballot(t == tt);
    if (mask) {
      int leader = __ffsll((long long)mask) - 1;
      if (lane == leader) atomicAdd(&cnt[tt], __popcll(mask));
    }
  }
}

__global__ void offs_kernel(const int* __restrict__ cnt, int* __restrict__ off) {
  int o = 0;
  off[0] = 0;
  for (int t = 0; t < 3; ++t) {
    o += ((cnt[t] + 63) >> 6) << 6;   // pad each bucket to 64
    off[t + 1] = o;
  }
}

__global__ __launch_bounds__(256) void fill_kernel(const int* __restrict__ ntype,
                                                   const int* __restrict__ off,
                                                   int* __restrict__ pos,
                                                   int* __restrict__ perm, int N) {
  int i = blockIdx.x * 256 + threadIdx.x;
  int lane = threadIdx.x & 63;
  int t = (i < N) ? ntype[i] : -1;
#pragma unroll
  for (int tt = 0; tt < 3; ++tt) {
    ull mask = __ballot(t == tt);
    if (mask) {
      int leader = __ffsll((long long)mask) - 1;
      int base = 0;
      if (lane == leader) base = atomicAdd(&pos[tt], __popcll(mask));
      base = __shfl(base, leader);
      if (t == tt) {
        int rank = __popcll(mask & ((lane == 63) ? 0x7fffffffffffffffull
                                                 : ((1ull << lane) - 1ull)));
        perm[off[tt] + base + rank] = i;
      }
    }
  }
}

// ---------------- MFMA QKV projection over type-sorted nodes ----------------
__global__ __launch_bounds__(256) void gemm_kernel(
    const float* __restrict__ X, const int* __restrict__ perm,
    const int* __restrict__ off, const ushort* __restrict__ Wp,
    const float* __restrict__ bq, const float* __restrict__ bk, const float* __restrict__ bv,
    float* __restrict__ Q, float* __restrict__ K, float* __restrict__ V) {
  __shared__ __align__(16) ushort As[64 * 136];   // pitch 136 -> 2-way LDS only (free)
  __shared__ int prow[64];
  const int tid = threadIdx.x;
  const int base = blockIdx.x * 64;
  const int off1 = off[1], off2 = off[2], off3 = off[3];
  if (base >= off3) return;
  const int t = (base >= off1) + (base >= off2);

  if (tid < 64) prow[tid] = perm[base + tid];
  __syncthreads();
#pragma unroll
  for (int pass = 0; pass < 16; ++pass) {
    int row = pass * 4 + (tid >> 6);
    int dw = tid & 63;
    int p = prow[row];
    uint u = 0u;
    if (p >= 0) {
      float2 xv = *(const float2*)(X + (size_t)p * 128 + dw * 2);
      u = ((uint)f2bf(xv.y) << 16) | (uint)f2bf(xv.x);
    }
    ((uint*)As)[row * 68 + dw] = u;
  }
  __syncthreads();

  const int lane = tid & 63;
  const int w = tid >> 6;
  const int m0 = w * 16;
  const int r = lane & 15;
  const int q = lane >> 4;

  f32x4 acc[3][8];
#pragma unroll
  for (int m = 0; m < 3; ++m)
#pragma unroll
    for (int ot = 0; ot < 8; ++ot) acc[m][ot] = (f32x4){0.f, 0.f, 0.f, 0.f};

  const ushort* wbase = Wp + (size_t)t * 16384;
#pragma unroll
  for (int ks = 0; ks < 4; ++ks) {
    short8 a = *(const short8*)(As + (m0 + r) * 136 + ks * 32 + q * 8);
#pragma unroll
    for (int mat = 0; mat < 3; ++mat) {
#pragma unroll
      for (int ot = 0; ot < 8; ++ot) {
        short8 b = *(const short8*)(wbase + mat * 49152 + (ot * 16 + r) * 128 + ks * 32 + q * 8);
        acc[mat][ot] = __builtin_amdgcn_mfma_f32_16x16x32_bf16(a, b, acc[mat][ot], 0, 0, 0);
      }
    }
  }

#pragma unroll
  for (int mat = 0; mat < 3; ++mat) {
    float* __restrict__ dstp = (mat == 0) ? Q : (mat == 1) ? K : V;
    const float* bias = (mat == 0) ? bq : (mat == 1) ? bk : bv;
#pragma unroll
    for (int ot = 0; ot < 8; ++ot) {
      int o = ot * 16 + r;
      float bi = bias[t * 128 + o];
#pragma unroll
      for (int reg = 0; reg < 4; ++reg) {
        int m = m0 + q * 4 + reg;
        int node = prow[m];
        if (node >= 0) dstp[(size_t)node * 128 + o] = acc[mat][ot][reg] + bi;
      }
    }
  }
}

// ---------------- CSR build: histogram, scan, scatter ----------------
__global__ __launch_bounds__(256) void ecount_kernel(const int* __restrict__ edst,
                                                     int* __restrict__ ecnt, int E) {
  int e = blockIdx.x * 256 + threadIdx.x;
  if (e < E) atomicAdd(&ecnt[edst[e]], 1);
}

// single-block two-level shuffle scan over N entries -> rowptr (excl) + cursor copy
__global__ __launch_bounds__(1024) void scan_kernel(const int* __restrict__ ecnt,
                                                    int* __restrict__ rowptr,
                                                    int* __restrict__ cursor, int N) {
  __shared__ int sdata[32];
  const int tid = threadIdx.x;
  const int lane = tid & 63;
  const int w = tid >> 6;     // 16 waves
  int soff = 0;
  for (int base = 0; base < N; base += 1024) {
    int i = base + tid;
    int v = (i < N) ? ecnt[i] : 0;
    int x = v;
#pragma unroll
    for (int d = 1; d < 64; d <<= 1) {
      int t = __shfl_up(x, d);
      if (lane >= d) x += t;
    }
    if (lane == 63) sdata[w] = x;
    __syncthreads();
    if (w == 0 && lane < 16) {
      int y = sdata[lane];
#pragma unroll
      for (int d = 1; d < 16; d <<= 1) {
        int t = __shfl_up(y, d);
        if (lane >= d) y += t;
      }
      sdata[16 + lane] = y;
    }
    __syncthreads();
    int excl = soff + ((w > 0) ? sdata[16 + w - 1] : 0) + (x - v);
    if (i < N) { rowptr[i] = excl; cursor[i] = excl; }
    soff += sdata[31];
    __syncthreads();
  }
  if (tid == 0) rowptr[N] = soff;
}

__global__ __launch_bounds__(256) void scatter_kernel(
    const int* __restrict__ esrc, const int* __restrict__ edst,
    const int* __restrict__ etype, const int* __restrict__ esign,
    const float* __restrict__ edist,
    const float* __restrict__ p_alpha, const float* __restrict__ p_tau,
    int* __restrict__ cursor,
    int* __restrict__ esrc_s, int* __restrict__ emeta_s, float* __restrict__ ephi_s, int E) {
  int e = blockIdx.x * 256 + threadIdx.x;
  if (e >= E) return;
  int dst = edst[e];
  int p = atomicAdd(&cursor[dst], 1);
  int et = etype[e], sg = esign[e];
  int sidx = (sg == -1) ? 0 : ((sg == 1) ? 1 : 2);
  float parg = fminf(fmaxf(-edist[e] / (p_tau[0] + 1e-9f), -80.f), 0.f);
  esrc_s[p] = esrc[e];
  emeta_s[p] = (et << 8) | (et * 3 + sidx);
  ephi_s[p] = p_alpha[0] * __expf(parg);
}

// ---------------- fused aggregation: one wave per dst ----------------
// softmax-normalize + gated residual + LayerNorm fused in the epilogue.
__global__ __launch_bounds__(256) void agg_kernel(
    const float* __restrict__ Q, const float* __restrict__ K, const float* __restrict__ V,
    const int* __restrict__ rowptr,
    const int* __restrict__ esrc_s, const int* __restrict__ emeta_s,
    const float* __restrict__ ephi_s,
    const float* __restrict__ rq, const float* __restrict__ rb,
    const float* __restrict__ rksk, const float* __restrict__ rvsv,
    const float* __restrict__ X, const int* __restrict__ ntype,
    const float* __restrict__ skip, const float* __restrict__ gamma,
    const float* __restrict__ beta, float* __restrict__ y, int N) {
  int dst = blockIdx.x * 4 + (threadIdx.x >> 6);
  if (dst >= N) return;
  int lane = threadIdx.x & 63;
  int c = lane * 2;
  int h = lane >> 3;

  float2 qv = *(const float2*)(Q + (size_t)dst * 128 + c);
  float2 acc; acc.x = 0.f; acc.y = 0.f;
  float z = 0.f;

  int row0 = rowptr[dst], row1 = rowptr[dst + 1];
  for (int base = row0; base < row1; base += 64) {
    int n = min(64, row1 - base);
    int srcv = 0, metav = 0;
    float phiv = 0.f;
    if (lane < n) {
      srcv = esrc_s[base + lane];
      metav = emeta_s[base + lane];
      phiv = ephi_s[base + lane];
    }
    for (int it = 0; it < n; ++it) {
      int srce = __shfl(srcv, it);
      int meta = __shfl(metav, it);
      float phi = __shfl(phiv, it);
      int comb = meta & 255;
      int et = meta >> 8;
      float2 kv = *(const float2*)(K + (size_t)srce * 128 + c);
      float2 vv = *(const float2*)(V + (size_t)srce * 128 + c);
      float2 rqv = *(const float2*)(rq + et * 128 + c);
      float2 kk = *(const float2*)(rksk + comb * 128 + c);
      float2 vk = *(const float2*)(rvsv + comb * 128 + c);
      float part = qv.x * rqv.x * kv.x * kk.x + qv.y * rqv.y * kv.y * kk.y;
      part += __shfl_xor(part, 1);
      part += __shfl_xor(part, 2);
      part += __shfl_xor(part, 4);
      float score = fminf(part * 0.25f + rb[et * 8 + h] + phi, 80.f);
      float es = __expf(score);
      z += es;
      acc.x = fmaf(es, vv.x * vk.x, acc.x);
      acc.y = fmaf(es, vv.y * vk.y, acc.y);
    }
  }

  float inv = 1.0f / (z + 1e-9f);
  float o0 = acc.x * inv, o1 = acc.y * inv;

  int t = ntype[dst];
  float a = 1.0f / (1.0f + __expf(-skip[t]));
  float2 xv = *(const float2*)(X + (size_t)dst * 128 + c);
  float v0 = a * o0 + (1.0f - a) * xv.x;
  float v1 = a * o1 + (1.0f - a) * xv.y;

  float sum = v0 + v1, sq = v0 * v0 + v1 * v1;
#pragma unroll
  for (int m = 1; m < 64; m <<= 1) {
    sum += __shfl_xor(sum, m);
    sq  += __shfl_xor(sq, m);
  }
  float mean = sum * (1.0f / 128.0f);
  float var = fmaxf(sq * (1.0f / 128.0f) - mean * mean, 0.0f);
  float rstd = rsqrtf(var + 1e-5f);

  float g0 = gamma[t * 128 + c], g1 = gamma[t * 128 + c + 1];
  float b0 = beta[t * 128 + c],  b1 = beta[t * 128 + c + 1];
  float2 o;
  o.x = (v0 - mean) * rstd * g0 + b0;
  o.y = (v1 - mean) * rstd * g1 + b1;
  *(float2*)(y + (size_t)dst * 128 + c) = o;
}

extern "C" void kernel_launch(void* const* d_in, const int* in_sizes, int n_in,
                              void* d_out, int out_size, void* d_ws, size_t ws_size,
                              hipStream_t stream) {
  const float* X     = (const float*)d_in[0];
  const int*   ntype = (const int*)d_in[1];
  const int*   eidx  = (const int*)d_in[2];     // [2,E]
  const int*   etype = (const int*)d_in[3];
  const int*   esign = (const int*)d_in[4];
  const float* edist = (const float*)d_in[5];
  const float* wq = (const float*)d_in[6];
  const float* bq = (const float*)d_in[7];
  const float* wk = (const float*)d_in[8];
  const float* bk = (const float*)d_in[9];
  const float* wv = (const float*)d_in[10];
  const float* bv = (const float*)d_in[11];
  const float* rq = (const float*)d_in[12];
  const float* rk = (const float*)d_in[13];
  const float* rv = (const float*)d_in[14];
  const float* rb = (const float*)d_in[15];

  const int N = in_sizes[1];
  const int E = in_sizes[3];

  float* ws = (float*)d_ws;
  const size_t NQ = (size_t)N * 128;
  float* Q    = ws;
  float* K    = ws + NQ;
  float* V    = ws + 2 * NQ;
  float* rksk = ws + 3 * NQ;                 // 3072
  float* rvsv = rksk + 3072;                 // 3072
  ushort* Wp  = (ushort*)(rvsv + 3072);      // 147456 ushorts = 73728 floats
  int* ibase  = (int*)(rvsv + 3072 + WP_ELEMS / 2);
  int* cnt    = ibase;                       // 4
  int* pos    = cnt + 4;                     // 4
  int* ecnt   = pos + 4;                     // N
  int* perm   = ecnt + N;                    // N+192
  int* off    = perm + N + 192;              // 4
  int* rowptr = off + 4;                     // N+1
  int* cursor = rowptr + N + 1;              // N
  int* esrc_s = cursor + N;                  // E
  int* emeta_s = esrc_s + E;                 // E
  float* ephi_s = (float*)(emeta_s + E);     // E

  hipMemsetAsync(cnt, 0, (size_t)(8 + N) * sizeof(int), stream);      // cnt,pos,ecnt
  hipMemsetAsync(perm, 0xFF, (size_t)(N + 192) * sizeof(int), stream);

  cvt_kernel<<<(WP_ELEMS + 255) / 256, 256, 0, stream>>>(
      wq, wk, wv, rk, rv, (const float*)d_in[16], (const float*)d_in[17],
      (const float*)d_in[18], (const float*)d_in[19], Wp, rksk, rvsv);
  count_kernel<<<(N + 255) / 256, 256, 0, stream>>>(ntype, cnt, N);
  offs_kernel<<<1, 1, 0, stream>>>(cnt, off);
  fill_kernel<<<(N + 255) / 256, 256, 0, stream>>>(ntype, off, pos, perm, N);

  ecount_kernel<<<(E + 255) / 256, 256, 0, stream>>>(eidx + E, ecnt, E);
  scan_kernel<<<1, 1024, 0, stream>>>(ecnt, rowptr, cursor, N);
  scatter_kernel<<<(E + 255) / 256, 256, 0, stream>>>(
      eidx, eidx + E, etype, esign, edist, (const float*)d_in[20], (const float*)d_in[21],
      cursor, esrc_s, emeta_s, ephi_s, E);

  gemm_kernel<<<(N + 255) / 64, 256, 0, stream>>>(X, perm, off, Wp, bq, bk, bv, Q, K, V);

  agg_kernel<<<(N + 3) / 4, 256, 0, stream>>>(Q, K, V, rowptr, esrc_s, emeta_s, ephi_s,
                                              rq, rb, rksk, rvsv, X, ntype,
                                              (const float*)d_in[22], (const float*)d_in[23],
                                              (const float*)d_in[24], (float*)d_out, N);
}

// Round 6
// 625.776 us; speedup vs baseline: 3.4205x; 1.2354x over previous
//
#include <hip/hip_runtime.h>
#include <hip/hip_bf16.h>

typedef unsigned int uint;
typedef unsigned short ushort;
typedef unsigned long long ull;
typedef __attribute__((ext_vector_type(8))) short short8;
typedef __attribute__((ext_vector_type(4))) float f32x4;

// packed transposed W (bf16): [mat][t][o][d], mat-major; 147456 ushorts
#define WP_ELEMS 147456

__device__ __forceinline__ float bf2f(ushort u) { return __uint_as_float(((uint)u) << 16); }
__device__ __forceinline__ ushort f2bf(float f) {
  uint x = __float_as_uint(f);
  return (ushort)((x + 0x7fffu + ((x >> 16) & 1u)) >> 16);
}

// ---- cvt: W (fp32) -> packed transposed bf16; fused rel*sign tables ----
__global__ __launch_bounds__(256) void cvt_kernel(
    const float* __restrict__ wq, const float* __restrict__ wk, const float* __restrict__ wv,
    const float* __restrict__ rk, const float* __restrict__ rv,
    const float* __restrict__ skf, const float* __restrict__ svf,
    const float* __restrict__ skn, const float* __restrict__ svn,
    ushort* __restrict__ Wp, float* __restrict__ rksk, float* __restrict__ rvsv) {
  int i = blockIdx.x * 256 + threadIdx.x;
  if (i < WP_ELEMS) {
    int mat = i / 49152;
    int rem = i - mat * 49152;
    int t = rem >> 14;
    int r2 = rem & 16383;
    int o = r2 >> 7;
    int d = r2 & 127;
    const float* src = (mat == 0) ? wq : (mat == 1) ? wk : wv;
    Wp[i] = f2bf(src[t * 16384 + d * 128 + o]);
  }
  if (i < 3072) {            // comb = et*3+sidx (24) x c (128)
    int comb = i >> 7, c = i & 127;
    int et = comb / 3, sidx = comb - et * 3;
    float skv = (sidx < 2) ? skf[sidx * 128 + c] : skn[c];
    float svv = (sidx < 2) ? svf[sidx * 128 + c] : svn[c];
    rksk[i] = rk[et * 128 + c] * skv;
    rvsv[i] = rv[et * 128 + c] * svv;
  }
}

// ---------------- node type bucketing ----------------
__global__ __launch_bounds__(256) void count_kernel(const int* __restrict__ ntype,
                                                    int* __restrict__ cnt, int N) {
  int i = blockIdx.x * 256 + threadIdx.x;
  int lane = threadIdx.x & 63;
  int t = (i < N) ? ntype[i] : -1;
#pragma unroll
  for (int tt = 0; tt < 3; ++tt) {
    ull mask = __ballot(t == tt);
    if (mask) {
      int leader = __ffsll((long long)mask) - 1;
      if (lane == leader) atomicAdd(&cnt[tt], __popcll(mask));
    }
  }
}

__global__ void offs_kernel(const int* __restrict__ cnt, int* __restrict__ off) {
  int o = 0;
  off[0] = 0;
  for (int t = 0; t < 3; ++t) {
    o += ((cnt[t] + 63) >> 6) << 6;   // pad each bucket to 64
    off[t + 1] = o;
  }
}

__global__ __launch_bounds__(256) void fill_kernel(const int* __restrict__ ntype,
                                                   const int* __restrict__ off,
                                                   int* __restrict__ pos,
                                                   int* __restrict__ perm,
                                                   int* __restrict__ pinv, int N) {
  int i = blockIdx.x * 256 + threadIdx.x;
  int lane = threadIdx.x & 63;
  int t = (i < N) ? ntype[i] : -1;
#pragma unroll
  for (int tt = 0; tt < 3; ++tt) {
    ull mask = __ballot(t == tt);
    if (mask) {
      int leader = __ffsll((long long)mask) - 1;
      int base = 0;
      if (lane == leader) base = atomicAdd(&pos[tt], __popcll(mask));
      base = __shfl(base, leader);
      if (t == tt) {
        int rank = __popcll(mask & ((lane == 63) ? 0x7fffffffffffffffull
                                                 : ((1ull << lane) - 1ull)));
        int p = off[tt] + base + rank;
        perm[p] = i;
        pinv[i] = p;
      }
    }
  }
}

// ---------------- MFMA QKV projection -> permuted-contiguous Qp / bf16 KVp ----------------
// 64 perm-rows/block, 4 waves x (16 rows x 128 cols) x 3 mats.
__global__ __launch_bounds__(256) void gemm_kernel(
    const float* __restrict__ X, const int* __restrict__ perm,
    const int* __restrict__ off, const ushort* __restrict__ Wp,
    const float* __restrict__ bq, const float* __restrict__ bk, const float* __restrict__ bv,
    float* __restrict__ Qp, uint* __restrict__ KVp) {
  __shared__ __align__(16) char smem[33792];   // As (17408B) then reused as tbuf (33792B)
  __shared__ int prow[64];
  ushort* As = (ushort*)smem;                  // pitch 136 -> 2-way LDS only (free)
  float* tbuf = (float*)smem;                  // per-wave 16x132 fp32 tile
  const int tid = threadIdx.x;
  const int base = blockIdx.x * 64;
  const int off1 = off[1], off2 = off[2], off3 = off[3];
  if (base >= off3) return;
  const int t = (base >= off1) + (base >= off2);

  if (tid < 64) prow[tid] = perm[base + tid];
  __syncthreads();
#pragma unroll
  for (int pass = 0; pass < 16; ++pass) {
    int row = pass * 4 + (tid >> 6);
    int dw = tid & 63;
    int p = prow[row];
    uint u = 0u;
    if (p >= 0) {
      float2 xv = *(const float2*)(X + (size_t)p * 128 + dw * 2);
      u = ((uint)f2bf(xv.y) << 16) | (uint)f2bf(xv.x);
    }
    ((uint*)smem)[row * 68 + dw] = u;
  }
  __syncthreads();

  const int lane = tid & 63;
  const int w = tid >> 6;
  const int m0 = w * 16;
  const int r = lane & 15;
  const int q = lane >> 4;

  f32x4 acc[3][8];
#pragma unroll
  for (int m = 0; m < 3; ++m)
#pragma unroll
    for (int ot = 0; ot < 8; ++ot) acc[m][ot] = (f32x4){0.f, 0.f, 0.f, 0.f};

  const ushort* wbase = Wp + (size_t)t * 16384;
#pragma unroll
  for (int ks = 0; ks < 4; ++ks) {
    short8 a = *(const short8*)(As + (m0 + r) * 136 + ks * 32 + q * 8);
#pragma unroll
    for (int mat = 0; mat < 3; ++mat) {
#pragma unroll
      for (int ot = 0; ot < 8; ++ot) {
        short8 b = *(const short8*)(wbase + mat * 49152 + (ot * 16 + r) * 128 + ks * 32 + q * 8);
        acc[mat][ot] = __builtin_amdgcn_mfma_f32_16x16x32_bf16(a, b, acc[mat][ot], 0, 0, 0);
      }
    }
  }

  __syncthreads();     // As dead; tbuf overwrites it
  float* tw = tbuf + w * 2112;   // 16 rows x pitch 132
#pragma unroll
  for (int mat = 0; mat < 3; ++mat) {
    const float* bias = (mat == 0) ? bq : (mat == 1) ? bk : bv;
    // C layout: col = ot*16 + r, row = q*4 + reg  -> LDS tile
#pragma unroll
    for (int ot = 0; ot < 8; ++ot) {
      float bi = bias[t * 128 + ot * 16 + r];
#pragma unroll
      for (int reg = 0; reg < 4; ++reg)
        tw[(q * 4 + reg) * 132 + ot * 16 + r] = acc[mat][ot][reg] + bi;
    }
    // per-wave private tile: no barrier needed between write and read
    if (mat == 0) {
#pragma unroll
      for (int p = 0; p < 8; ++p) {
        int f = (p * 64 + lane) * 4;
        int row = f >> 7, col = f & 127;
        float4 val = *(const float4*)(tw + row * 132 + col);
        *(float4*)(Qp + (size_t)(base + m0 + row) * 128 + col) = val;
      }
    } else {
      uint vbase = (mat == 2) ? 64u : 0u;
#pragma unroll
      for (int p = 0; p < 4; ++p) {
        int g = p * 64 + lane;
        int f = g * 8;
        int row = f >> 7, col = f & 127;
        const float* src = tw + row * 132 + col;
        float4 a4 = *(const float4*)(src);
        float4 b4 = *(const float4*)(src + 4);
        uint4 u;
        u.x = ((uint)f2bf(a4.y) << 16) | (uint)f2bf(a4.x);
        u.y = ((uint)f2bf(a4.w) << 16) | (uint)f2bf(a4.z);
        u.z = ((uint)f2bf(b4.y) << 16) | (uint)f2bf(b4.x);
        u.w = ((uint)f2bf(b4.w) << 16) | (uint)f2bf(b4.z);
        *(uint4*)(KVp + (size_t)(base + m0 + row) * 128 + vbase + (uint)(col >> 1)) = u;
      }
    }
  }
}

// ---------------- CSR build: histogram, 3-phase scan, scatter ----------------
__global__ __launch_bounds__(256) void ecount_kernel(const int* __restrict__ edst,
                                                     int* __restrict__ ecnt, int E) {
  int e = blockIdx.x * 256 + threadIdx.x;
  if (e < E) atomicAdd(&ecnt[edst[e]], 1);
}

__global__ __launch_bounds__(256) void csum_kernel(const int* __restrict__ ecnt,
                                                   int* __restrict__ csum, int N) {
  __shared__ int s[4];
  int basei = blockIdx.x * 1024;
  int tid = threadIdx.x;
  int v = 0;
#pragma unroll
  for (int k = 0; k < 4; ++k) {
    int i = basei + k * 256 + tid;
    if (i < N) v += ecnt[i];
  }
#pragma unroll
  for (int m = 1; m < 64; m <<= 1) v += __shfl_xor(v, m);
  if ((tid & 63) == 0) s[tid >> 6] = v;
  __syncthreads();
  if (tid == 0) csum[blockIdx.x] = s[0] + s[1] + s[2] + s[3];
}

__global__ __launch_bounds__(1024) void cscan_kernel(const int* __restrict__ csum,
                                                     int* __restrict__ coff,
                                                     int* __restrict__ rowptrN,
                                                     int NC, int E) {
  __shared__ int sd[32];
  int tid = threadIdx.x, lane = tid & 63, w = tid >> 6;
  int v = (tid < NC) ? csum[tid] : 0;
  int x = v;
#pragma unroll
  for (int d = 1; d < 64; d <<= 1) {
    int t = __shfl_up(x, d);
    if (lane >= d) x += t;
  }
  if (lane == 63) sd[w] = x;
  __syncthreads();
  if (w == 0 && lane < 16) {
    int y = sd[lane];
#pragma unroll
    for (int d = 1; d < 16; d <<= 1) {
      int t = __shfl_up(y, d);
      if (lane >= d) y += t;
    }
    sd[16 + lane] = y;
  }
  __syncthreads();
  int excl = ((w > 0) ? sd[16 + w - 1] : 0) + (x - v);
  if (tid < NC) coff[tid] = excl;
  if (tid == 0) rowptrN[0] = E;
}

__global__ __launch_bounds__(1024) void rowptr_kernel(const int* __restrict__ ecnt,
                                                      const int* __restrict__ coff,
                                                      int* __restrict__ rowptr,
                                                      int* __restrict__ cursor, int N) {
  __shared__ int sd[32];
  int basei = blockIdx.x * 1024;
  int tid = threadIdx.x, lane = tid & 63, w = tid >> 6;
  int i = basei + tid;
  int v = (i < N) ? ecnt[i] : 0;
  int x = v;
#pragma unroll
  for (int d = 1; d < 64; d <<= 1) {
    int t = __shfl_up(x, d);
    if (lane >= d) x += t;
  }
  if (lane == 63) sd[w] = x;
  __syncthreads();
  if (w == 0 && lane < 16) {
    int y = sd[lane];
#pragma unroll
    for (int d = 1; d < 16; d <<= 1) {
      int t = __shfl_up(y, d);
      if (lane >= d) y += t;
    }
    sd[16 + lane] = y;
  }
  __syncthreads();
  int excl = coff[blockIdx.x] + ((w > 0) ? sd[16 + w - 1] : 0) + (x - v);
  if (i < N) { rowptr[i] = excl; cursor[i] = excl; }
}

__global__ __launch_bounds__(256) void scatter_kernel(
    const int* __restrict__ esrc, const int* __restrict__ edst,
    const int* __restrict__ etype, const int* __restrict__ esign,
    const float* __restrict__ edist,
    const float* __restrict__ p_alpha, const float* __restrict__ p_tau,
    const int* __restrict__ pinv, int* __restrict__ cursor,
    int* __restrict__ esrc_s, int* __restrict__ emeta_s, float* __restrict__ ephi_s, int E) {
  int e = blockIdx.x * 256 + threadIdx.x;
  if (e >= E) return;
  int dst = edst[e];
  int p = atomicAdd(&cursor[dst], 1);
  int et = etype[e], sg = esign[e];
  int sidx = (sg == -1) ? 0 : ((sg == 1) ? 1 : 2);
  float parg = fminf(fmaxf(-edist[e] / (p_tau[0] + 1e-9f), -80.f), 0.f);
  esrc_s[p] = pinv[esrc[e]];           // pre-fold permuted src row
  emeta_s[p] = (et << 8) | (et * 3 + sidx);
  ephi_s[p] = p_alpha[0] * __expf(parg);
}

// ---------------- fused aggregation: one wave per dst ----------------
__global__ __launch_bounds__(256) void agg_kernel(
    const float* __restrict__ Qp, const uint* __restrict__ KVp,
    const int* __restrict__ pinv, const int* __restrict__ rowptr,
    const int* __restrict__ esrc_s, const int* __restrict__ emeta_s,
    const float* __restrict__ ephi_s,
    const float* __restrict__ rq, const float* __restrict__ rb,
    const float* __restrict__ rksk, const float* __restrict__ rvsv,
    const float* __restrict__ X, const int* __restrict__ ntype,
    const float* __restrict__ skip, const float* __restrict__ gamma,
    const float* __restrict__ beta, float* __restrict__ y, int N) {
  int dst = blockIdx.x * 4 + (threadIdx.x >> 6);
  if (dst >= N) return;
  int lane = threadIdx.x & 63;
  int c = lane * 2;
  int h = lane >> 3;

  int pq = pinv[dst];
  float2 qv = *(const float2*)(Qp + (size_t)pq * 128 + c);
  float2 acc; acc.x = 0.f; acc.y = 0.f;
  float z = 0.f;

  int row0 = rowptr[dst], row1 = rowptr[dst + 1];
  for (int bb = row0; bb < row1; bb += 64) {
    int n = min(64, row1 - bb);
    int srcv = 0, metav = 0;
    float phiv = 0.f;
    if (lane < n) {
      srcv = esrc_s[bb + lane];
      metav = emeta_s[bb + lane];
      phiv = ephi_s[bb + lane];
    }
    for (int it = 0; it < n; ++it) {
      int pe = __shfl(srcv, it);
      int meta = __shfl(metav, it);
      float phi = __shfl(phiv, it);
      int comb = meta & 255;
      int et = meta >> 8;
      uint ku = KVp[(size_t)pe * 128 + lane];
      uint vu = KVp[(size_t)pe * 128 + 64 + lane];
      float2 rqv = *(const float2*)(rq + et * 128 + c);
      float2 kk = *(const float2*)(rksk + comb * 128 + c);
      float2 vk = *(const float2*)(rvsv + comb * 128 + c);
      float kx = bf2f((ushort)(ku & 0xffffu)), ky = bf2f((ushort)(ku >> 16));
      float vx = bf2f((ushort)(vu & 0xffffu)), vy = bf2f((ushort)(vu >> 16));
      float part = qv.x * rqv.x * kx * kk.x + qv.y * rqv.y * ky * kk.y;
      part += __shfl_xor(part, 1);
      part += __shfl_xor(part, 2);
      part += __shfl_xor(part, 4);
      float score = fminf(part * 0.25f + rb[et * 8 + h] + phi, 80.f);
      float es = __expf(score);
      z += es;
      acc.x = fmaf(es, vx * vk.x, acc.x);
      acc.y = fmaf(es, vy * vk.y, acc.y);
    }
  }

  float inv = 1.0f / (z + 1e-9f);
  float o0 = acc.x * inv, o1 = acc.y * inv;

  int t = ntype[dst];
  float a = 1.0f / (1.0f + __expf(-skip[t]));
  float2 xv = *(const float2*)(X + (size_t)dst * 128 + c);
  float v0 = a * o0 + (1.0f - a) * xv.x;
  float v1 = a * o1 + (1.0f - a) * xv.y;

  float sum = v0 + v1, sq = v0 * v0 + v1 * v1;
#pragma unroll
  for (int m = 1; m < 64; m <<= 1) {
    sum += __shfl_xor(sum, m);
    sq  += __shfl_xor(sq, m);
  }
  float mean = sum * (1.0f / 128.0f);
  float var = fmaxf(sq * (1.0f / 128.0f) - mean * mean, 0.0f);
  float rstd = rsqrtf(var + 1e-5f);

  float g0 = gamma[t * 128 + c], g1 = gamma[t * 128 + c + 1];
  float b0 = beta[t * 128 + c],  b1 = beta[t * 128 + c + 1];
  float2 o;
  o.x = (v0 - mean) * rstd * g0 + b0;
  o.y = (v1 - mean) * rstd * g1 + b1;
  *(float2*)(y + (size_t)dst * 128 + c) = o;
}

extern "C" void kernel_launch(void* const* d_in, const int* in_sizes, int n_in,
                              void* d_out, int out_size, void* d_ws, size_t ws_size,
                              hipStream_t stream) {
  const float* X     = (const float*)d_in[0];
  const int*   ntype = (const int*)d_in[1];
  const int*   eidx  = (const int*)d_in[2];     // [2,E]
  const int*   etype = (const int*)d_in[3];
  const int*   esign = (const int*)d_in[4];
  const float* edist = (const float*)d_in[5];
  const float* wq = (const float*)d_in[6];
  const float* bq = (const float*)d_in[7];
  const float* wk = (const float*)d_in[8];
  const float* bk = (const float*)d_in[9];
  const float* wv = (const float*)d_in[10];
  const float* bv = (const float*)d_in[11];
  const float* rq = (const float*)d_in[12];
  const float* rk = (const float*)d_in[13];
  const float* rv = (const float*)d_in[14];
  const float* rb = (const float*)d_in[15];

  const int N = in_sizes[1];
  const int E = in_sizes[3];
  const int NP = N + 192;          // permuted rows incl. bucket padding
  const int NC = (N + 1023) / 1024;

  float* ws = (float*)d_ws;
  float* Qp   = ws;                               // NP*128 fp32
  uint*  KVp  = (uint*)(Qp + (size_t)NP * 128);   // NP*128 uints (K:0..63, V:64..127)
  float* rksk = (float*)(KVp + (size_t)NP * 128); // 3072
  float* rvsv = rksk + 3072;                      // 3072
  ushort* Wp  = (ushort*)(rvsv + 3072);           // 147456
  int* cnt    = (int*)(Wp + WP_ELEMS);            // 4
  int* pos    = cnt + 4;                          // 4
  int* ecnt   = pos + 4;                          // N
  int* perm   = ecnt + N;                         // NP
  int* pinv   = perm + NP;                        // N
  int* off    = pinv + N;                         // 4
  int* rowptr = off + 4;                          // N+1
  int* cursor = rowptr + N + 1;                   // N
  int* csum   = cursor + N;                       // 1024
  int* coff   = csum + 1024;                      // 1024
  int* esrc_s = coff + 1024;                      // E
  int* emeta_s = esrc_s + E;                      // E
  float* ephi_s = (float*)(emeta_s + E);          // E

  hipMemsetAsync(cnt, 0, (size_t)(8 + N) * sizeof(int), stream);   // cnt,pos,ecnt
  hipMemsetAsync(perm, 0xFF, (size_t)NP * sizeof(int), stream);

  cvt_kernel<<<(WP_ELEMS + 255) / 256, 256, 0, stream>>>(
      wq, wk, wv, rk, rv, (const float*)d_in[16], (const float*)d_in[17],
      (const float*)d_in[18], (const float*)d_in[19], Wp, rksk, rvsv);
  count_kernel<<<(N + 255) / 256, 256, 0, stream>>>(ntype, cnt, N);
  offs_kernel<<<1, 1, 0, stream>>>(cnt, off);
  fill_kernel<<<(N + 255) / 256, 256, 0, stream>>>(ntype, off, pos, perm, pinv, N);

  ecount_kernel<<<(E + 255) / 256, 256, 0, stream>>>(eidx + E, ecnt, E);
  csum_kernel<<<NC, 256, 0, stream>>>(ecnt, csum, N);
  cscan_kernel<<<1, 1024, 0, stream>>>(csum, coff, rowptr + N, NC, E);
  rowptr_kernel<<<NC, 1024, 0, stream>>>(ecnt, coff, rowptr, cursor, N);
  scatter_kernel<<<(E + 255) / 256, 256, 0, stream>>>(
      eidx, eidx + E, etype, esign, edist, (const float*)d_in[20], (const float*)d_in[21],
      pinv, cursor, esrc_s, emeta_s, ephi_s, E);

  gemm_kernel<<<(N + 255) / 64, 256, 0, stream>>>(X, perm, off, Wp, bq, bk, bv, Qp, KVp);

  agg_kernel<<<(N + 3) / 4, 256, 0, stream>>>(Qp, KVp, pinv, rowptr, esrc_s, emeta_s,
                                              ephi_s, rq, rb, rksk, rvsv, X, ntype,
                                              (const float*)d_in[22], (const float*)d_in[23],
                                              (const float*)d_in[24], (float*)d_out, N);
}